// Round 9
// baseline (255.910 us; speedup 1.0000x reference)
//
#include <hip/hip_runtime.h>

typedef __bf16 bf16_t;
typedef __bf16 bf16x8 __attribute__((ext_vector_type(8)));
typedef __bf16 bf16x4 __attribute__((ext_vector_type(4)));
typedef float f32x4 __attribute__((ext_vector_type(4)));

#define GLOAD_LDS16(gptr, lptr)                                                              \
  __builtin_amdgcn_global_load_lds((const __attribute__((address_space(1))) void*)(gptr),    \
                                   (__attribute__((address_space(3))) void*)(lptr), 16, 0, 0)

__device__ __forceinline__ f32x4 f32x4_zero() {
  f32x4 v; v[0] = 0.f; v[1] = 0.f; v[2] = 0.f; v[3] = 0.f; return v;
}

// 4-bit XOR swizzle key: rows 8 apart get distinct keys -> V-transpose column reads
// (rows {r, r+8, r+16, r+24}) hit disjoint bank columns.
__device__ __forceinline__ int kxr(int r) { return (r & 7) ^ (((r >> 3) & 3) << 1); }

// ---------------------------------------------------------------- fused casts f32 -> bf16
__global__ void cast3_kernel(const float* __restrict__ a, const float* __restrict__ b,
                             const float* __restrict__ c, bf16_t* __restrict__ oa,
                             bf16_t* __restrict__ ob, bf16_t* __restrict__ oc) {
  int i = blockIdx.x * blockDim.x + threadIdx.x;
  const float* src; bf16_t* dst; int j;
  if (i < 2097152) { src = a; dst = oa; j = i; }
  else if (i < 2883584) { src = b; dst = ob; j = i - 2097152; }
  else { src = c; dst = oc; j = i - 2883584; }
  float4 v = ((const float4*)src)[j];
  bf16x4 o;
  o[0] = (bf16_t)v.x; o[1] = (bf16_t)v.y; o[2] = (bf16_t)v.z; o[3] = (bf16_t)v.w;
  ((bf16x4*)dst)[j] = o;
}

// ---------------------------------------------------------------- GEMM  C[M,N] = A[M,K] * B[N,K]^T
// MODE 0: write fp32 C row-major.  MODE 1: scatter bf16 qkv into head layout [4,16,2048,64].
template <int MODE>
__global__ __launch_bounds__(256) void gemm_bt_kernel(
    const bf16_t* __restrict__ A, const bf16_t* __restrict__ B, float* __restrict__ C,
    bf16_t* __restrict__ oq, bf16_t* __restrict__ ok_, bf16_t* __restrict__ ov,
    int M, int N, int K) {
  constexpr int BM = 128, BN = 128, BK = 32;
  __shared__ bf16_t As[BM * BK];
  __shared__ bf16_t Bs[BN * BK];
  const int tid = threadIdx.x;
  const int lane = tid & 63;
  const int wid = tid >> 6;
  const int wm = (wid >> 1) * 64;
  const int wn = (wid & 1) * 64;
  const int l16 = lane & 15;
  const int qd = lane >> 4;
  const int bm = blockIdx.x, bn = blockIdx.y;

  const int srow = tid >> 2;
  const int skol = (tid & 3) * 8;

  const bf16_t* gA = A + (size_t)(bm * BM + srow) * K + skol;
  const bf16_t* gB = B + (size_t)(bn * BN + srow) * K + skol;
  bf16_t* lA = &As[srow * BK + skol];
  bf16_t* lB = &Bs[srow * BK + skol];

  f32x4 acc[4][4];
#pragma unroll
  for (int mb = 0; mb < 4; mb++)
#pragma unroll
    for (int nb = 0; nb < 4; nb++) acc[mb][nb] = f32x4_zero();

  for (int k0 = 0; k0 < K; k0 += BK) {
    __syncthreads();
    GLOAD_LDS16(gA + k0, lA);
    GLOAD_LDS16(gA + (size_t)64 * K + k0, lA + 64 * BK);
    GLOAD_LDS16(gB + k0, lB);
    GLOAD_LDS16(gB + (size_t)64 * K + k0, lB + 64 * BK);
    __syncthreads();

    bf16x8 af[4], bfr[4];
#pragma unroll
    for (int mb = 0; mb < 4; mb++)
      af[mb] = *(const bf16x8*)&As[(wm + mb * 16 + l16) * BK + qd * 8];
#pragma unroll
    for (int nb = 0; nb < 4; nb++)
      bfr[nb] = *(const bf16x8*)&Bs[(wn + nb * 16 + l16) * BK + qd * 8];
#pragma unroll
    for (int mb = 0; mb < 4; mb++)
#pragma unroll
      for (int nb = 0; nb < 4; nb++)
        acc[mb][nb] = __builtin_amdgcn_mfma_f32_16x16x32_bf16(af[mb], bfr[nb], acc[mb][nb], 0, 0, 0);
  }

  if (MODE == 0) {
#pragma unroll
    for (int mb = 0; mb < 4; mb++)
#pragma unroll
      for (int nb = 0; nb < 4; nb++)
#pragma unroll
        for (int r = 0; r < 4; r++) {
          int row = bm * BM + wm + mb * 16 + qd * 4 + r;
          int col = bn * BN + wn + nb * 16 + l16;
          C[(size_t)row * N + col] = acc[mb][nb][r];
        }
  } else {
    const int part = bn >> 3;
    const int h = ((bn * 128 + wn) & 1023) >> 6;
    bf16_t* dst = (part == 0) ? oq : (part == 1) ? ok_ : ov;
#pragma unroll
    for (int mb = 0; mb < 4; mb++)
#pragma unroll
      for (int r = 0; r < 4; r++) {
        int row = bm * BM + wm + mb * 16 + qd * 4 + r;
        int b = row >> 11, t = row & 2047;
        size_t basei = (((size_t)(b * 16 + h)) * 2048 + t) * 64;
#pragma unroll
        for (int nb = 0; nb < 4; nb++)
          dst[basei + nb * 16 + l16] = (bf16_t)acc[mb][nb][r];
      }
  }
}

// ---------------------------------------------------------------- standalone RoPE pre-pass
// In-place on qhp/khp ([bh][t][64]); q also gets 0.125*log2(e). 2M threads, 8B vector ops.
__global__ void ropeqk_kernel(bf16_t* __restrict__ qh, bf16_t* __restrict__ kh,
                              const float* __restrict__ cosp, const float* __restrict__ sinp) {
  int gid = blockIdx.x * 256 + threadIdx.x;  // 0 .. 2*1048576
  bool isq = gid < 1048576;
  int ii = gid & 1048575;
  bf16_t* ptr = isq ? qh : kh;
  const float sc = isq ? 0.18033688011112042f : 1.0f;
  int d0 = (ii & 7) * 4;
  int t = (ii >> 3) & 2047;
  int bh = ii >> 14;
  size_t base = ((size_t)bh * 2048 + t) * 64;
  bf16x4 lo = *(bf16x4*)&ptr[base + d0];
  bf16x4 hi = *(bf16x4*)&ptr[base + d0 + 32];
  float4 cl = *(const float4*)&cosp[t * 64 + d0];
  float4 ch = *(const float4*)&cosp[t * 64 + d0 + 32];
  float4 sl = *(const float4*)&sinp[t * 64 + d0];
  float4 sh = *(const float4*)&sinp[t * 64 + d0 + 32];
  bf16x4 ol, oh;
  ol[0] = (bf16_t)(((float)lo[0] * cl.x - (float)hi[0] * sl.x) * sc);
  ol[1] = (bf16_t)(((float)lo[1] * cl.y - (float)hi[1] * sl.y) * sc);
  ol[2] = (bf16_t)(((float)lo[2] * cl.z - (float)hi[2] * sl.z) * sc);
  ol[3] = (bf16_t)(((float)lo[3] * cl.w - (float)hi[3] * sl.w) * sc);
  oh[0] = (bf16_t)(((float)hi[0] * ch.x + (float)lo[0] * sh.x) * sc);
  oh[1] = (bf16_t)(((float)hi[1] * ch.y + (float)lo[1] * sh.y) * sc);
  oh[2] = (bf16_t)(((float)hi[2] * ch.z + (float)lo[2] * sh.z) * sc);
  oh[3] = (bf16_t)(((float)hi[3] * ch.w + (float)lo[3] * sh.w) * sc);
  *(bf16x4*)&ptr[base + d0] = ol;
  *(bf16x4*)&ptr[base + d0 + 32] = oh;
}

// ---------------------------------------------------------------- banded flash attention
// block = (b*16+h, i0/128): BQ=128 queries, 4 waves; wave w owns rows [32w,32w+32) = 2 sub-tiles.
// Q staged once -> A-frags in REGISTERS; its 16KB LDS is then reused as the P buffer.
// 3 barriers/chunk, no rope in loop (pre-passed), fixed-max exp2 softmax, ones-MFMA row sums.
__global__ __launch_bounds__(256, 3) void attn_kernel(
    const bf16_t* __restrict__ qh, const bf16_t* __restrict__ kh,
    const bf16_t* __restrict__ vh, bf16_t* __restrict__ ao) {
  __shared__ bf16_t qps[128 * 64];     // Q (prologue) then P (main loop)
  __shared__ bf16_t ks[64 * 64];
  __shared__ bf16_t vs[64 * 64];
  __shared__ bf16_t vswz[8 * 64 * 8];  // [kk*4+nb][lane][jj]

  const int tid = threadIdx.x;
  const int lane = tid & 63;
  const int wid = tid >> 6;
  const int l16 = lane & 15;
  const int qd = lane >> 4;

  const int bh = blockIdx.x;        // 0..63
  const int i0 = blockIdx.y * 128;  // query tile base
  const int b = bh >> 4, h = bh & 15;
  const int r0 = tid >> 3, q0 = tid & 7;

  {  // stage Q tile (r&7-key swizzle)
    const uint4* qsrc = (const uint4*)(qh + ((size_t)bh * 2048 + i0) * 64);
    uint4* q4 = (uint4*)qps;
#pragma unroll
    for (int p = 0; p < 4; p++) {
      int f = p * 256 + tid, rr = f >> 3;
      q4[rr * 8 + ((f & 7) ^ (rr & 7))] = qsrc[f];
    }
  }
  __syncthreads();

  bf16x8 qfrag[2][2];
#pragma unroll
  for (int mb = 0; mb < 2; mb++)
#pragma unroll
    for (int kk = 0; kk < 2; kk++) {
      int row = wid * 32 + mb * 16 + l16;
      qfrag[mb][kk] = *(const bf16x8*)&qps[row * 64 + (((kk * 4 + qd) ^ (l16 & 7)) * 8)];
    }
  // qps is now free for reuse as P (first P write happens after barrier B of chunk 1,
  // by which point every wave has passed barrier A, hence read its Q-frags).

  bf16x8 bones;
#pragma unroll
  for (int e = 0; e < 8; e++) bones[e] = (bf16_t)1.0f;

  float l_i[2][4] = {{0.f, 0.f, 0.f, 0.f}, {0.f, 0.f, 0.f, 0.f}};
  f32x4 oacc[2][4];
#pragma unroll
  for (int mb = 0; mb < 2; mb++)
#pragma unroll
    for (int nb = 0; nb < 4; nb++) oacc[mb][nb] = f32x4_zero();

  const int ct = i0 >> 6;
  const int c1 = ct + 1;
  const int c0 = (ct >= 4) ? (ct - 4) : 0;
  const uint4* ksrc = (const uint4*)(kh + (size_t)bh * 2048 * 64);
  const uint4* vsrc = (const uint4*)(vh + (size_t)bh * 2048 * 64);
  uint4* k4 = (uint4*)ks;
  uint4* v4 = (uint4*)vs;

  for (int c = c0; c <= c1; c++) {
    const int j0 = c * 64;
    __syncthreads();  // A: prior ps/vswz reads (and prologue qfrag reads) complete
    k4[r0 * 8 + (q0 ^ (r0 & 7))] = ksrc[c * 512 + tid];
    k4[(r0 + 32) * 8 + (q0 ^ ((r0 + 32) & 7))] = ksrc[c * 512 + tid + 256];
    v4[r0 * 8 + (q0 ^ kxr(r0))] = vsrc[c * 512 + tid];
    v4[(r0 + 32) * 8 + (q0 ^ kxr(r0 + 32))] = vsrc[c * 512 + tid + 256];
    __syncthreads();  // B: ks/vs published

    // S = Q K^T for both sub-tiles (scale+log2e pre-folded into q)
    f32x4 sacc[2][4];
#pragma unroll
    for (int mb = 0; mb < 2; mb++)
#pragma unroll
      for (int nb = 0; nb < 4; nb++) sacc[mb][nb] = f32x4_zero();
#pragma unroll
    for (int kk = 0; kk < 2; kk++) {
#pragma unroll
      for (int nb = 0; nb < 4; nb++) {
        int brow = nb * 16 + l16;
        bf16x8 bfr = *(const bf16x8*)&ks[brow * 64 + (((kk * 4 + qd) ^ (brow & 7)) * 8)];
        sacc[0][nb] = __builtin_amdgcn_mfma_f32_16x16x32_bf16(qfrag[0][kk], bfr, sacc[0][nb], 0, 0, 0);
        sacc[1][nb] = __builtin_amdgcn_mfma_f32_16x16x32_bf16(qfrag[1][kk], bfr, sacc[1][nb], 0, 0, 0);
      }
    }

    // LDS transpose: vs -> vswz (exact PV B-fragment order); kxr staging -> conflict-free
#pragma unroll
    for (int p2 = 0; p2 < 2; p2++) {
      int combo = p2 * 4 + wid;  // kk*4+nb, uniform per wave
      int jbase = (combo >> 2) * 32 + (lane >> 4) * 8;
      int dcol = (combo & 3) * 16 + (lane & 15);
      int bb = dcol >> 3, dlo = dcol & 7;
      bf16x8 v8;
#pragma unroll
      for (int e = 0; e < 8; e++) {
        int row = jbase + e;
        v8[e] = vs[row * 64 + ((bb ^ kxr(row)) * 8) + dlo];
      }
      *(bf16x8*)&vswz[(combo * 64 + lane) * 8] = v8;
    }

    // fixed-max softmax: p = exp2(s) (masked -> 0), written into the reused Q buffer
#pragma unroll
    for (int mb = 0; mb < 2; mb++)
#pragma unroll
      for (int r = 0; r < 4; r++) {
        const int i = i0 + wid * 32 + mb * 16 + qd * 4 + r;
        const int prow = qd * 4 + r;
        const int rowp = wid * 32 + mb * 16 + prow;
#pragma unroll
        for (int nb = 0; nb < 4; nb++) {
          const int j = j0 + nb * 16 + l16;
          bool valid = (j <= i) && (j + 256 > i);
          float p = valid ? exp2f(sacc[mb][nb][r]) : 0.f;
          qps[rowp * 64 + (((nb * 2 + (l16 >> 3)) ^ (prow & 7)) * 8) + (l16 & 7)] = (bf16_t)p;
        }
      }

    __syncthreads();  // C: ps/vswz published

    // O += P V ; l += P * ones
    f32x4 lacc[2];
    lacc[0] = f32x4_zero(); lacc[1] = f32x4_zero();
#pragma unroll
    for (int kk = 0; kk < 2; kk++) {
      bf16x8 afr0 = *(const bf16x8*)&qps[(wid * 32 + l16) * 64 + (((kk * 4 + qd) ^ (l16 & 7)) * 8)];
      bf16x8 afr1 = *(const bf16x8*)&qps[(wid * 32 + 16 + l16) * 64 + (((kk * 4 + qd) ^ (l16 & 7)) * 8)];
      lacc[0] = __builtin_amdgcn_mfma_f32_16x16x32_bf16(afr0, bones, lacc[0], 0, 0, 0);
      lacc[1] = __builtin_amdgcn_mfma_f32_16x16x32_bf16(afr1, bones, lacc[1], 0, 0, 0);
#pragma unroll
      for (int nb = 0; nb < 4; nb++) {
        bf16x8 bfr = *(const bf16x8*)&vswz[((kk * 4 + nb) * 64 + lane) * 8];
        oacc[0][nb] = __builtin_amdgcn_mfma_f32_16x16x32_bf16(afr0, bfr, oacc[0][nb], 0, 0, 0);
        oacc[1][nb] = __builtin_amdgcn_mfma_f32_16x16x32_bf16(afr1, bfr, oacc[1][nb], 0, 0, 0);
      }
    }
#pragma unroll
    for (int mb = 0; mb < 2; mb++)
#pragma unroll
      for (int r = 0; r < 4; r++) l_i[mb][r] += lacc[mb][r];
  }

  // epilogue: ao[b][t][h*64+d] = O/l
#pragma unroll
  for (int mb = 0; mb < 2; mb++)
#pragma unroll
    for (int nb = 0; nb < 4; nb++)
#pragma unroll
      for (int r = 0; r < 4; r++) {
        int t = i0 + wid * 32 + mb * 16 + qd * 4 + r;
        ao[((size_t)(b * 2048 + t)) * 1024 + h * 64 + nb * 16 + l16] =
            (bf16_t)(oacc[mb][nb][r] / l_i[mb][r]);
      }
}

// ---------------------------------------------------------------- launch
extern "C" void kernel_launch(void* const* d_in, const int* in_sizes, int n_in,
                              void* d_out, int out_size, void* d_ws, size_t ws_size,
                              hipStream_t stream) {
  const float* x    = (const float*)d_in[0];  // [4,2048,1024]
  const float* cosp = (const float*)d_in[1];  // [1,2048,1,64]
  const float* sinp = (const float*)d_in[2];
  const float* qkvw = (const float*)d_in[3];  // [3072,1024]
  const float* outw = (const float*)d_in[4];  // [1024,1024]
  float* out = (float*)d_out;                 // [4,2048,1024]

  char* ws = (char*)d_ws;
  bf16_t* xb  = (bf16_t*)(ws + 0);
  bf16_t* qwb = (bf16_t*)(ws + 16777216);
  bf16_t* owb = (bf16_t*)(ws + 23068672);
  bf16_t* qhp = (bf16_t*)(ws + 25165824);   // [B,H,T,64] bf16
  bf16_t* khp = (bf16_t*)(ws + 41943040);
  bf16_t* vhp = (bf16_t*)(ws + 58720256);
  bf16_t* aop = (bf16_t*)(ws + 75497472);   // [B,T,1024] bf16

  cast3_kernel<<<12288, 256, 0, stream>>>(x, qkvw, outw, xb, qwb, owb);

  gemm_bt_kernel<1><<<dim3(64, 24), 256, 0, stream>>>(xb, qwb, nullptr, qhp, khp, vhp,
                                                      8192, 3072, 1024);
  ropeqk_kernel<<<8192, 256, 0, stream>>>(qhp, khp, cosp, sinp);
  attn_kernel<<<dim3(64, 16), 256, 0, stream>>>(qhp, khp, vhp, aop);
  gemm_bt_kernel<0><<<dim3(64, 8), 256, 0, stream>>>(aop, owb, out, nullptr, nullptr, nullptr,
                                                     8192, 1024, 1024);
}